// Round 1
// baseline (100.623 us; speedup 1.0000x reference)
//
#include <hip/hip_runtime.h>
#include <hip/hip_bf16.h>

// Problem constants
constexpr int B        = 1024;
constexpr int IN_BITS  = 4096;
constexpr int NUM_LUTS = 16384;
constexpr int K        = 6;

constexpr int TPB        = 256;       // threads per block
constexpr int LUTS_PER_B = 256;       // luts per block (== TPB, 1 lut/thread)
constexpr int CHUNKS     = 8;         // batch chunks
constexpr int BCH        = B / CHUNKS; // 128 batch rows per block

// -----------------------------------------------------------------------------
// Kernel 1: binarize + batch-transposed bit-pack.
// packedT[g * IN_BITS + pos], bit j = (x_bits[(g*32+j)][pos] > 0.5)
// Lanes map to consecutive pos -> both loads and stores fully coalesced.
// -----------------------------------------------------------------------------
__global__ __launch_bounds__(TPB) void pack_kernel(
    const float* __restrict__ x, unsigned* __restrict__ packedT)
{
    const int pos = blockIdx.x * TPB + threadIdx.x;   // 0..4095
    const int g   = blockIdx.y;                       // 0..31 (batch word)
    const float* xp = x + (size_t)g * 32 * IN_BITS + pos;
    unsigned word = 0;
#pragma unroll
    for (int j = 0; j < 32; ++j) {
        word |= (xp[(size_t)j * IN_BITS] > 0.5f) ? (1u << j) : 0u;
    }
    packedT[(size_t)g * IN_BITS + pos] = word;
}

// -----------------------------------------------------------------------------
// Kernel 2: LUT evaluation.
// grid.x = NUM_LUTS / LUTS_PER_B (64), grid.y = CHUNKS (8)
// Each block: stage 256 LUT rows (64 KiB) into LDS, then loop 128 batch rows.
// Per 32-batch group: 6 global word-gathers per thread, then 32 iterations of
// VALU-only index building + LDS table gather + coalesced store.
// -----------------------------------------------------------------------------
__global__ __launch_bounds__(TPB, 2) void lut_kernel(
    const float*    __restrict__ table,
    const int*      __restrict__ conn,
    const unsigned* __restrict__ packedT,
    float*          __restrict__ out)
{
    __shared__ float tbl[LUTS_PER_B * 64];   // 64 KiB, flat [lut_local][idx]

    const int tid = threadIdx.x;
    const int l0  = blockIdx.x * LUTS_PER_B;
    const int l   = l0 + tid;

    // Stage table slice: 16384 floats via float4, coalesced, conflict-free LDS.
    {
        const float4* tsrc = (const float4*)(table + (size_t)l0 * 64);
        float4*       tdst = (float4*)tbl;
#pragma unroll
        for (int i = 0; i < 16; ++i) {
            tdst[tid + i * TPB] = tsrc[tid + i * TPB];
        }
    }

    // Per-thread connection indices (cached in registers for the whole block).
    int c[K];
#pragma unroll
    for (int k = 0; k < K; ++k) c[k] = conn[(size_t)l * K + k];

    __syncthreads();

    const int bbase = blockIdx.y * BCH;
    float* op = out + (size_t)bbase * NUM_LUTS + l;

    for (int g = 0; g < BCH / 32; ++g) {
        const unsigned* pr = packedT + (size_t)(bbase / 32 + g) * IN_BITS;
        unsigned w[K];
#pragma unroll
        for (int k = 0; k < K; ++k) w[k] = pr[c[k]];   // 6 gathers / 32 batches

#pragma unroll
        for (int j = 0; j < 32; ++j) {
            int idx = 0;
#pragma unroll
            for (int k = 0; k < K; ++k)
                idx = (idx << 1) | (int)((w[k] >> j) & 1u);  // c[0] is MSB
            float v = tbl[tid * 64 + idx];
            // sigmoid
            float s = 1.0f / (1.0f + __expf(-v));
            *op = s;
            op += NUM_LUTS;
        }
    }
}

extern "C" void kernel_launch(void* const* d_in, const int* in_sizes, int n_in,
                              void* d_out, int out_size, void* d_ws, size_t ws_size,
                              hipStream_t stream)
{
    const float* x_bits = (const float*)d_in[0];
    const float* table  = (const float*)d_in[1];
    const int*   conn   = (const int*)d_in[2];
    float* out = (float*)d_out;
    unsigned* packedT = (unsigned*)d_ws;   // 32 * 4096 * 4 B = 512 KiB

    dim3 g1(IN_BITS / TPB, B / 32);        // (16, 32)
    pack_kernel<<<g1, TPB, 0, stream>>>(x_bits, packedT);

    dim3 g2(NUM_LUTS / LUTS_PER_B, CHUNKS); // (64, 8)
    lut_kernel<<<g2, TPB, 0, stream>>>(table, conn, packedT, out);
}

// Round 2
// 94.882 us; speedup vs baseline: 1.0605x; 1.0605x over previous
//
#include <hip/hip_runtime.h>
#include <hip/hip_bf16.h>

// Problem constants
constexpr int B        = 1024;
constexpr int IN_BITS  = 4096;
constexpr int NUM_LUTS = 16384;
constexpr int K        = 6;

constexpr int TPB        = 256;        // threads per block
constexpr int LUTS_PER_B = 256;        // luts per block (== TPB, 1 lut/thread)
constexpr int CHUNKS     = 8;          // batch chunks
constexpr int BCH        = B / CHUNKS; // 128 batch rows per chunk-block

constexpr int PACK_BLOCKS = (IN_BITS / TPB) * (B / 32); // 512
constexpr int TBL_BLOCKS  = NUM_LUTS / 64;              // 256

// -----------------------------------------------------------------------------
// Prep kernel (fused):
//  blocks [0, PACK_BLOCKS): binarize x into batch-transposed bit words
//     packedT[g*IN_BITS + pos], bit j = (x[(g*32+j)][pos] > 0.5)
//  blocks [PACK_BLOCKS, +TBL_BLOCKS): transpose table -> tableT[entry][lut]
//     with sigmoid pre-applied (1M evals instead of 16.8M in the hot loop).
//     Transposed layout makes the hot-loop LDS gather bank-conflict-FREE:
//     read addr = idx*256 + tid -> bank = tid & 31 (distinct per lane).
// -----------------------------------------------------------------------------
__global__ __launch_bounds__(TPB) void prep_kernel(
    const float* __restrict__ x, const float* __restrict__ table,
    unsigned* __restrict__ packedT, float* __restrict__ tableT)
{
    __shared__ float tile[64][65];   // +1 pad: conflict-light transpose
    const int tid = threadIdx.x;
    const int blk = blockIdx.x;

    if (blk < PACK_BLOCKS) {
        const int pos = (blk % (IN_BITS / TPB)) * TPB + tid;  // coalesced
        const int g   = blk / (IN_BITS / TPB);                // batch word
        const float* xp = x + (size_t)g * 32 * IN_BITS + pos;
        unsigned word = 0;
#pragma unroll
        for (int j = 0; j < 32; ++j)
            word |= (xp[(size_t)j * IN_BITS] > 0.5f) ? (1u << j) : 0u;
        packedT[(size_t)g * IN_BITS + pos] = word;
    } else {
        const int bt = blk - PACK_BLOCKS;  // 0..255, 64 luts each
        const int l0 = bt * 64;
        // Coalesced read of the 64x64 fp32 tile (luts x entries)
        const float4* src = (const float4*)(table + (size_t)l0 * 64);
#pragma unroll
        for (int i = 0; i < 4; ++i) {
            int q = tid + i * 256;        // float4 index, 0..1023
            float4 v = src[q];
            int l = q >> 4;               // lut within tile
            int e = (q & 15) * 4;         // entry
            tile[l][e + 0] = v.x; tile[l][e + 1] = v.y;
            tile[l][e + 2] = v.z; tile[l][e + 3] = v.w;
        }
        __syncthreads();
        // Write transposed + sigmoid, coalesced float4 along lut dim
#pragma unroll
        for (int i = 0; i < 4; ++i) {
            int q  = tid + i * 256;
            int e  = q >> 4;              // entry (row of tableT)
            int lc = (q & 15) * 4;        // lut within tile
            float4 v;
            v.x = 1.0f / (1.0f + __expf(-tile[lc + 0][e]));
            v.y = 1.0f / (1.0f + __expf(-tile[lc + 1][e]));
            v.z = 1.0f / (1.0f + __expf(-tile[lc + 2][e]));
            v.w = 1.0f / (1.0f + __expf(-tile[lc + 3][e]));
            ((float4*)(tableT + (size_t)e * NUM_LUTS + l0))[q & 15] = v;
        }
    }
}

// -----------------------------------------------------------------------------
// LUT kernel: grid (NUM_LUTS/256, CHUNKS). Stage 256 sigmoid'd LUT rows in
// transposed layout tbl[entry*256 + lut_local] (64 KiB). Hot loop: 6 bit
// extracts -> conflict-free LDS gather -> nontemporal coalesced store.
// -----------------------------------------------------------------------------
__global__ __launch_bounds__(TPB, 2) void lut_kernel(
    const int*      __restrict__ conn,
    const unsigned* __restrict__ packedT,
    const float*    __restrict__ tableT,
    float*          __restrict__ out)
{
    __shared__ float tbl[64 * LUTS_PER_B];   // [entry][lut_local], 64 KiB

    const int tid = threadIdx.x;
    const int l0  = blockIdx.x * LUTS_PER_B;
    const int l   = l0 + tid;

    // Stage: coalesced float4 global reads -> conflict-free b128 LDS writes
    {
        float4* dst = (float4*)tbl;
#pragma unroll
        for (int i = 0; i < 16; ++i) {
            int q = tid + i * 256;   // float4 index, 0..4095
            int e = q >> 6;          // entry row
            int c = q & 63;          // float4 within row
            dst[q] = ((const float4*)(tableT + (size_t)e * NUM_LUTS + l0))[c];
        }
    }

    int c[K];
#pragma unroll
    for (int k = 0; k < K; ++k) c[k] = conn[(size_t)l * K + k];

    __syncthreads();

    const int bbase = blockIdx.y * BCH;
    float* op = out + (size_t)bbase * NUM_LUTS + l;

    for (int g = 0; g < BCH / 32; ++g) {
        const unsigned* pr = packedT + (size_t)(bbase / 32 + g) * IN_BITS;
        unsigned w[K];
#pragma unroll
        for (int k = 0; k < K; ++k) w[k] = pr[c[k]];  // 6 L1-hot gathers / 32 rows

#pragma unroll
        for (int j = 0; j < 32; ++j) {
            int idx = 0;
#pragma unroll
            for (int k = 0; k < K; ++k)
                idx = (idx << 1) | (int)((w[k] >> j) & 1u);  // c[0] = MSB
            float v = tbl[idx * LUTS_PER_B + tid];  // bank = tid&31: conflict-free
            __builtin_nontemporal_store(v, op);     // streaming 64 MiB output
            op += NUM_LUTS;
        }
    }
}

extern "C" void kernel_launch(void* const* d_in, const int* in_sizes, int n_in,
                              void* d_out, int out_size, void* d_ws, size_t ws_size,
                              hipStream_t stream)
{
    const float* x_bits = (const float*)d_in[0];
    const float* table  = (const float*)d_in[1];
    const int*   conn   = (const int*)d_in[2];
    float* out = (float*)d_out;

    unsigned* packedT = (unsigned*)d_ws;                          // 512 KiB
    float*    tableT  = (float*)((char*)d_ws + 512 * 1024);       // 4 MiB

    prep_kernel<<<PACK_BLOCKS + TBL_BLOCKS, TPB, 0, stream>>>(
        x_bits, table, packedT, tableT);

    dim3 g2(NUM_LUTS / LUTS_PER_B, CHUNKS);  // (64, 8)
    lut_kernel<<<g2, TPB, 0, stream>>>(conn, packedT, tableT, out);
}

// Round 3
// 93.546 us; speedup vs baseline: 1.0757x; 1.0143x over previous
//
#include <hip/hip_runtime.h>
#include <hip/hip_bf16.h>

// Problem constants
constexpr int B        = 1024;
constexpr int IN_BITS  = 4096;
constexpr int NUM_LUTS = 16384;
constexpr int K        = 6;

constexpr int TPB        = 256;        // threads per block
constexpr int LUTS_PER_B = 256;        // luts per block (== TPB, 1 lut/thread)
constexpr int CHUNKS     = 16;         // batch chunks (64 rows each)
constexpr int BCH        = B / CHUNKS; // 64 batch rows per chunk-block

constexpr int PACK_BLOCKS = (IN_BITS / TPB) * (B / 32); // 512
constexpr int TBL_BLOCKS  = NUM_LUTS / 64;              // 256

// fp32 -> bf16 round-to-nearest-even (values are finite, no NaN handling)
__device__ inline unsigned short f2bf(float f) {
    unsigned u = __float_as_uint(f);
    return (unsigned short)((u + 0x7FFFu + ((u >> 16) & 1u)) >> 16);
}

// -----------------------------------------------------------------------------
// Prep kernel (fused):
//  blocks [0, PACK_BLOCKS): binarize x into batch-transposed bit words
//     packedT[g*IN_BITS + pos], bit j = (x[(g*32+j)][pos] > 0.5)
//  blocks [PACK_BLOCKS, +TBL_BLOCKS): transpose table -> tableT[entry][lut]
//     with sigmoid pre-applied (1M evals, hoisted out of the 16.8M hot loop)
//     and bf16 conversion (sigmoid in [0,1]: abs err ~1e-3 << 1.02e-2 thresh).
// -----------------------------------------------------------------------------
__global__ __launch_bounds__(TPB) void prep_kernel(
    const float* __restrict__ x, const float* __restrict__ table,
    unsigned* __restrict__ packedT, unsigned short* __restrict__ tableT)
{
    __shared__ float tile[64][65];   // +1 pad: conflict-light transpose
    const int tid = threadIdx.x;
    const int blk = blockIdx.x;

    if (blk < PACK_BLOCKS) {
        const int pos = (blk % (IN_BITS / TPB)) * TPB + tid;  // coalesced
        const int g   = blk / (IN_BITS / TPB);                // batch word
        const float* xp = x + (size_t)g * 32 * IN_BITS + pos;
        unsigned word = 0;
#pragma unroll
        for (int j = 0; j < 32; ++j)
            word |= (xp[(size_t)j * IN_BITS] > 0.5f) ? (1u << j) : 0u;
        packedT[(size_t)g * IN_BITS + pos] = word;
    } else {
        const int bt = blk - PACK_BLOCKS;  // 0..255, 64 luts each
        const int l0 = bt * 64;
        // Coalesced read of the 64x64 fp32 tile (luts x entries)
        const float4* src = (const float4*)(table + (size_t)l0 * 64);
#pragma unroll
        for (int i = 0; i < 4; ++i) {
            int q = tid + i * 256;        // float4 index, 0..1023
            float4 v = src[q];
            int l = q >> 4;               // lut within tile
            int e = (q & 15) * 4;         // entry
            tile[l][e + 0] = v.x; tile[l][e + 1] = v.y;
            tile[l][e + 2] = v.z; tile[l][e + 3] = v.w;
        }
        __syncthreads();
        // Write transposed + sigmoid + bf16, packed 4 luts per ushort4 store
#pragma unroll
        for (int i = 0; i < 4; ++i) {
            int q  = tid + i * 256;
            int e  = q >> 4;              // entry (row of tableT)
            int lc = (q & 15) * 4;        // lut within tile
            ushort4 v;
            v.x = f2bf(1.0f / (1.0f + __expf(-tile[lc + 0][e])));
            v.y = f2bf(1.0f / (1.0f + __expf(-tile[lc + 1][e])));
            v.z = f2bf(1.0f / (1.0f + __expf(-tile[lc + 2][e])));
            v.w = f2bf(1.0f / (1.0f + __expf(-tile[lc + 3][e])));
            ((ushort4*)(tableT + (size_t)e * NUM_LUTS + l0))[q & 15] = v;
        }
    }
}

// -----------------------------------------------------------------------------
// LUT kernel: grid (NUM_LUTS/256, CHUNKS=16). Stage 256 sigmoid'd bf16 LUT
// rows in transposed layout tbl[entry*256 + lut_local] (32 KiB -> 4 blocks/CU,
// 16 waves/CU). Hot loop: 6 bit extracts -> conflict-free ds_read_u16
// (bank = tid>>1, 2 lanes/bank = free) -> bf16->f32 shift -> nontemporal store.
// -----------------------------------------------------------------------------
__global__ __launch_bounds__(TPB, 4) void lut_kernel(
    const int*            __restrict__ conn,
    const unsigned*       __restrict__ packedT,
    const unsigned short* __restrict__ tableT,
    float*                __restrict__ out)
{
    __shared__ unsigned short tbl[64 * LUTS_PER_B];   // [entry][lut_local], 32 KiB

    const int tid = threadIdx.x;
    const int l0  = blockIdx.x * LUTS_PER_B;
    const int l   = l0 + tid;

    // Stage 32 KiB: coalesced uint4 global reads -> b128 LDS writes
    {
        uint4* dst = (uint4*)tbl;
#pragma unroll
        for (int i = 0; i < 8; ++i) {
            int q = tid + i * 256;   // uint4 index, 0..2047
            int e = q >> 5;          // entry row (32 uint4 per 256-bf16 row)
            int p = q & 31;
            dst[q] = ((const uint4*)(tableT + (size_t)e * NUM_LUTS + l0))[p];
        }
    }

    int c[K];
#pragma unroll
    for (int k = 0; k < K; ++k) c[k] = conn[(size_t)l * K + k];

    __syncthreads();

    const int bbase = blockIdx.y * BCH;
    float* op = out + (size_t)bbase * NUM_LUTS + l;

#pragma unroll
    for (int g = 0; g < BCH / 32; ++g) {
        const unsigned* pr = packedT + (size_t)(bbase / 32 + g) * IN_BITS;
        unsigned w[K];
#pragma unroll
        for (int k = 0; k < K; ++k) w[k] = pr[c[k]];  // 6 L1-hot gathers / 32 rows

#pragma unroll
        for (int j = 0; j < 32; ++j) {
            int idx = 0;
#pragma unroll
            for (int k = 0; k < K; ++k)
                idx = (idx << 1) | (int)((w[k] >> j) & 1u);  // c[0] = MSB
            unsigned short h = tbl[idx * LUTS_PER_B + tid];  // conflict-free
            float v = __uint_as_float((unsigned)h << 16);    // bf16 -> f32
            __builtin_nontemporal_store(v, op);              // streaming output
            op += NUM_LUTS;
        }
    }
}

extern "C" void kernel_launch(void* const* d_in, const int* in_sizes, int n_in,
                              void* d_out, int out_size, void* d_ws, size_t ws_size,
                              hipStream_t stream)
{
    const float* x_bits = (const float*)d_in[0];
    const float* table  = (const float*)d_in[1];
    const int*   conn   = (const int*)d_in[2];
    float* out = (float*)d_out;

    unsigned*       packedT = (unsigned*)d_ws;                       // 512 KiB
    unsigned short* tableT  = (unsigned short*)((char*)d_ws + 512 * 1024); // 2 MiB

    prep_kernel<<<PACK_BLOCKS + TBL_BLOCKS, TPB, 0, stream>>>(
        x_bits, table, packedT, tableT);

    dim3 g2(NUM_LUTS / LUTS_PER_B, CHUNKS);  // (64, 16)
    lut_kernel<<<g2, TPB, 0, stream>>>(conn, packedT, tableT, out);
}